// Round 3
// baseline (1083.957 us; speedup 1.0000x reference)
//
#include <hip/hip_runtime.h>

typedef unsigned short ushort_t;
typedef unsigned int uint_t;
typedef __attribute__((ext_vector_type(8))) short short8;
typedef __attribute__((ext_vector_type(4))) float f32x4;

#define Bv 16
#define Lv 1025
#define LpD 1088          // 17*64 padded sequence
#define Cv 1024
#define Hv 16
#define BHv 256
#define Mv 16400          // valid rows
#define Mp 16512          // 129*128 padded rows

#define MFMA(a, b, c) __builtin_amdgcn_mfma_f32_16x16x32_bf16(a, b, c, 0, 0, 0)

__device__ __forceinline__ ushort_t f2b(float x) {
    uint_t u = __float_as_uint(x);
    u = (u + 0x7FFFu + ((u >> 16) & 1u)) >> 16;   // RNE
    return (ushort_t)u;
}
__device__ __forceinline__ float b2f(ushort_t v) {
    return __uint_as_float(((uint_t)v) << 16);
}

// ---------------- fp32 -> bf16 convert (pads tail with zeros) ---------------
__global__ __launch_bounds__(256) void conv_bf16(const float* __restrict__ s,
                                                 ushort_t* __restrict__ d,
                                                 int n_valid, int n_total) {
    int i = (blockIdx.x * 256 + threadIdx.x) * 4;
    if (i >= n_total) return;
    float4 v = make_float4(0.f, 0.f, 0.f, 0.f);
    if (i < n_valid) v = *(const float4*)(s + i);   // n_valid multiple of 4
    ushort4 o;
    o.x = f2b(v.x); o.y = f2b(v.y); o.z = f2b(v.z); o.w = f2b(v.w);
    *(ushort4*)(d + i) = o;
}

// ---------------- QKV GEMM: C[m][n] = sum_k A[m][k] W[n][k], scatter --------
// Epilogue stages the 128x128 bf16 C-tile in LDS (stride 132: quadrant rows
// are 4 apart -> 8-bank offsets, conflict-free), then stores full 128-B lines.
__global__ __launch_bounds__(256, 2) void gemm_qkv(const ushort_t* __restrict__ A,
                                                   const ushort_t* __restrict__ W,
                                                   ushort_t* __restrict__ Q,
                                                   ushort_t* __restrict__ K,
                                                   ushort_t* __restrict__ V) {
    __shared__ ushort_t sm[2][128][72];   // 36864 B; K-loop tiles + epilogue staging
    ushort_t (&As)[128][72] = sm[0];
    ushort_t (&Bs)[128][72] = sm[1];
    const int t = threadIdx.x;
    const int w = t >> 6, l = t & 63;
    const int m0 = blockIdx.y * 128, n0 = blockIdx.x * 128;
    const int wm = (w >> 1) * 64, wn = (w & 1) * 64;
    f32x4 acc[4][4] = {};
    uint4 pa[4], pb[4];
#pragma unroll
    for (int i = 0; i < 4; i++) {
        int c = t + 256 * i; int row = c >> 3, cir = c & 7;
        pa[i] = *(const uint4*)(A + (size_t)(m0 + row) * 1024 + cir * 8);
        pb[i] = *(const uint4*)(W + (size_t)(n0 + row) * 1024 + cir * 8);
    }
    for (int k0 = 0; k0 < 1024; k0 += 64) {
        __syncthreads();
#pragma unroll
        for (int i = 0; i < 4; i++) {
            int c = t + 256 * i; int row = c >> 3, cir = c & 7;
            *(uint4*)&As[row][cir * 8] = pa[i];
            *(uint4*)&Bs[row][cir * 8] = pb[i];
        }
        __syncthreads();
        if (k0 + 64 < 1024) {
#pragma unroll
            for (int i = 0; i < 4; i++) {
                int c = t + 256 * i; int row = c >> 3, cir = c & 7;
                pa[i] = *(const uint4*)(A + (size_t)(m0 + row) * 1024 + k0 + 64 + cir * 8);
                pb[i] = *(const uint4*)(W + (size_t)(n0 + row) * 1024 + k0 + 64 + cir * 8);
            }
        }
#pragma unroll
        for (int kb = 0; kb < 2; kb++) {
            short8 af[4], bf[4];
#pragma unroll
            for (int mb = 0; mb < 4; mb++)
                af[mb] = *(const short8*)&As[wm + mb * 16 + (l & 15)][kb * 32 + (l >> 4) * 8];
#pragma unroll
            for (int nb = 0; nb < 4; nb++)
                bf[nb] = *(const short8*)&Bs[wn + nb * 16 + (l & 15)][kb * 32 + (l >> 4) * 8];
#pragma unroll
            for (int mb = 0; mb < 4; mb++)
#pragma unroll
                for (int nb = 0; nb < 4; nb++)
                    acc[mb][nb] = MFMA(af[mb], bf[nb], acc[mb][nb]);
        }
    }
    // ---- epilogue: LDS-staged, coalesced 128-B stores ----
    __syncthreads();
    ushort_t (*St)[132] = (ushort_t(*)[132])&sm[0][0][0];   // 128x132 bf16 = 33792 B
#pragma unroll
    for (int mb = 0; mb < 4; mb++)
#pragma unroll
        for (int r = 0; r < 4; r++)
#pragma unroll
            for (int nb = 0; nb < 4; nb++)
                St[wm + mb * 16 + (l >> 4) * 4 + r][wn + nb * 16 + (l & 15)] =
                    f2b(acc[mb][nb][r]);
    __syncthreads();
    // 256 segments (row, head-half p): each 8-lane group stores 128 B.
#pragma unroll
    for (int it = 0; it < 8; it++) {
        int seg = it * 32 + w * 8 + (l >> 3);
        int mr = seg >> 1, p = seg & 1;
        int m = m0 + mr;
        if (m < Mv) {
            int b = m / 1025, lseq = m - b * 1025;
            int n = n0 + p * 64;
            int which = n >> 10, h = (n >> 6) & 15;
            ushort_t* dst = (which == 0) ? Q : ((which == 1) ? K : V);
            *(uint4*)(dst + ((size_t)(b * Hv + h) * LpD + lseq) * 64 + (l & 7) * 8) =
                *(const uint4*)&St[mr][p * 64 + (l & 7) * 8];
        }
    }
}

// ---------------- RoPE in-place on bf16 Q,K (rows l=1..1024) ----------------
__global__ __launch_bounds__(256) void rope_bf16(ushort_t* __restrict__ Qb,
                                                 ushort_t* __restrict__ Kb,
                                                 const float* __restrict__ sinp,
                                                 const float* __restrict__ cosp) {
    const int ROWS = BHv * 1024;
    int row = blockIdx.x * 4 + (threadIdx.x >> 6);
    int d = threadIdx.x & 63;
    ushort_t* arr = (row < ROWS) ? Qb : Kb;
    int r = (row < ROWS) ? row : row - ROWS;
    int bh = r >> 10, lm1 = r & 1023;
    size_t a = ((size_t)bh * LpD + lm1 + 1) * 64 + d;
    float f = b2f(arr[a]);
    float p = __shfl_xor(f, 32);
    p = (d < 32) ? -p : p;
    arr[a] = f2b(f * cosp[lm1 * 64 + d] + p * sinp[lm1 * 64 + d]);
}

// ---------------- V transpose: [BH][Lp][64] -> [BH][64][Lp] -----------------
__global__ __launch_bounds__(256) void transpose_v(const ushort_t* __restrict__ Vb,
                                                   ushort_t* __restrict__ Vt) {
    __shared__ ushort_t Ts[64][72];
    const int t = threadIdx.x;
    const int l0 = blockIdx.x * 64, bh = blockIdx.y;
#pragma unroll
    for (int i = 0; i < 2; i++) {
        int c = t + 256 * i; int row = c >> 3, cir = c & 7;
        *(uint4*)&Ts[row][cir * 8] =
            *(const uint4*)(Vb + ((size_t)bh * LpD + l0 + row) * 64 + cir * 8);
    }
    __syncthreads();
#pragma unroll
    for (int i = 0; i < 2; i++) {
        int c = t + 256 * i; int d = c >> 3, lg = c & 7;
        short8 v;
#pragma unroll
        for (int j = 0; j < 8; j++) v[j] = (short)Ts[lg * 8 + j][d];
        *(short8*)(Vt + ((size_t)bh * 64 + d) * LpD + l0 + lg * 8) = v;
    }
}

// ---------------- Attention: block = (q-tile 64, bh). Unnormalized exp. -----
__global__ __launch_bounds__(256, 4) void attn_mfma(const ushort_t* __restrict__ Qb,
                                                    const ushort_t* __restrict__ Kb,
                                                    const ushort_t* __restrict__ Vt,
                                                    ushort_t* __restrict__ AO) {
    __shared__ ushort_t Qs[64][72], Ks[64][72], Vs[64][72], Ps[64][72];
    const int t = threadIdx.x, w = t >> 6, l = t & 63;
    const int qt = blockIdx.x, bh = blockIdx.y;
    const int q0 = qt * 64;
    const size_t kbase = (size_t)bh * LpD * 64;
    const size_t vbase = (size_t)bh * 64 * LpD;
#pragma unroll
    for (int i = 0; i < 2; i++) {
        int c = t + 256 * i; int row = c >> 3, cir = c & 7;
        *(uint4*)&Qs[row][cir * 8] =
            *(const uint4*)(Qb + kbase + (size_t)(q0 + row) * 64 + cir * 8);
    }
    __syncthreads();
    // Q A-frags live in registers for the whole K loop
    short8 aq0 = *(const short8*)&Qs[w * 16 + (l & 15)][(l >> 4) * 8];
    short8 aq1 = *(const short8*)&Qs[w * 16 + (l & 15)][32 + (l >> 4) * 8];
    f32x4 o[4] = {};
    float sume[4] = {0.f, 0.f, 0.f, 0.f};
    const float CE = 0.18033688011112042f;  // log2(e)/8: exp(s/8) = exp2(s*CE)

    for (int kt = 0; kt < 17; kt++) {
        __syncthreads();
#pragma unroll
        for (int i = 0; i < 2; i++) {
            int c = t + 256 * i; int row = c >> 3, cir = c & 7;
            *(uint4*)&Ks[row][cir * 8] =
                *(const uint4*)(Kb + kbase + (size_t)(kt * 64 + row) * 64 + cir * 8);
            *(uint4*)&Vs[row][cir * 8] =
                *(const uint4*)(Vt + vbase + (size_t)row * LpD + kt * 64 + cir * 8);
        }
        __syncthreads();
#pragma unroll
        for (int cb = 0; cb < 4; cb++) {
            short8 bk0 = *(const short8*)&Ks[cb * 16 + (l & 15)][(l >> 4) * 8];
            short8 bk1 = *(const short8*)&Ks[cb * 16 + (l & 15)][32 + (l >> 4) * 8];
            f32x4 s = {};
            s = MFMA(aq0, bk0, s);
            s = MFMA(aq1, bk1, s);
            int key = kt * 64 + cb * 16 + (l & 15);
            bool valid = key < Lv;   // padded keys must contribute exactly 0
#pragma unroll
            for (int r = 0; r < 4; r++) {
                float p = valid ? exp2f(s[r] * CE) : 0.f;
                sume[r] += p;
                Ps[w * 16 + (l >> 4) * 4 + r][cb * 16 + (l & 15)] = f2b(p);
            }
        }
        // own-wave rows only -> no barrier; compiler inserts lgkmcnt waits
        short8 ap0 = *(const short8*)&Ps[w * 16 + (l & 15)][(l >> 4) * 8];
        short8 ap1 = *(const short8*)&Ps[w * 16 + (l & 15)][32 + (l >> 4) * 8];
#pragma unroll
        for (int cb = 0; cb < 4; cb++) {
            short8 bv0 = *(const short8*)&Vs[cb * 16 + (l & 15)][(l >> 4) * 8];
            short8 bv1 = *(const short8*)&Vs[cb * 16 + (l & 15)][32 + (l >> 4) * 8];
            o[cb] = MFMA(ap0, bv0, o[cb]);
            o[cb] = MFMA(ap1, bv1, o[cb]);
        }
    }
#pragma unroll
    for (int r = 0; r < 4; r++) {
        float s_ = sume[r];
        s_ += __shfl_xor(s_, 1); s_ += __shfl_xor(s_, 2);
        s_ += __shfl_xor(s_, 4); s_ += __shfl_xor(s_, 8);
        sume[r] = 1.f / s_;      // row sums; row map matches C-layout rows
    }
    const int b = bh >> 4, h = bh & 15;
#pragma unroll
    for (int r = 0; r < 4; r++) {
        int lq = q0 + w * 16 + (l >> 4) * 4 + r;
        if (lq >= Lv) continue;
        size_t ob = ((size_t)(b * 1025 + lq)) * 1024 + h * 64;
#pragma unroll
        for (int cb = 0; cb < 4; cb++)
            AO[ob + cb * 16 + (l & 15)] = f2b(o[cb][r] * sume[r]);
    }
}

// ---------------- Proj GEMM + bias, fp32 out, LDS-staged epilogue -----------
__global__ __launch_bounds__(256, 2) void gemm_proj(const ushort_t* __restrict__ A,
                                                    const ushort_t* __restrict__ W,
                                                    const float* __restrict__ bias,
                                                    float* __restrict__ out) {
    __shared__ ushort_t sm[2][128][72];
    ushort_t (&As)[128][72] = sm[0];
    ushort_t (&Bs)[128][72] = sm[1];
    const int t = threadIdx.x;
    const int w = t >> 6, l = t & 63;
    const int m0 = blockIdx.y * 128, n0 = blockIdx.x * 128;
    const int wm = (w >> 1) * 64, wn = (w & 1) * 64;
    f32x4 acc[4][4] = {};
    uint4 pa[4], pb[4];
#pragma unroll
    for (int i = 0; i < 4; i++) {
        int c = t + 256 * i; int row = c >> 3, cir = c & 7;
        pa[i] = *(const uint4*)(A + (size_t)(m0 + row) * 1024 + cir * 8);
        pb[i] = *(const uint4*)(W + (size_t)(n0 + row) * 1024 + cir * 8);
    }
    for (int k0 = 0; k0 < 1024; k0 += 64) {
        __syncthreads();
#pragma unroll
        for (int i = 0; i < 4; i++) {
            int c = t + 256 * i; int row = c >> 3, cir = c & 7;
            *(uint4*)&As[row][cir * 8] = pa[i];
            *(uint4*)&Bs[row][cir * 8] = pb[i];
        }
        __syncthreads();
        if (k0 + 64 < 1024) {
#pragma unroll
            for (int i = 0; i < 4; i++) {
                int c = t + 256 * i; int row = c >> 3, cir = c & 7;
                pa[i] = *(const uint4*)(A + (size_t)(m0 + row) * 1024 + k0 + 64 + cir * 8);
                pb[i] = *(const uint4*)(W + (size_t)(n0 + row) * 1024 + k0 + 64 + cir * 8);
            }
        }
#pragma unroll
        for (int kb = 0; kb < 2; kb++) {
            short8 af[4], bf[4];
#pragma unroll
            for (int mb = 0; mb < 4; mb++)
                af[mb] = *(const short8*)&As[wm + mb * 16 + (l & 15)][kb * 32 + (l >> 4) * 8];
#pragma unroll
            for (int nb = 0; nb < 4; nb++)
                bf[nb] = *(const short8*)&Bs[wn + nb * 16 + (l & 15)][kb * 32 + (l >> 4) * 8];
#pragma unroll
            for (int mb = 0; mb < 4; mb++)
#pragma unroll
                for (int nb = 0; nb < 4; nb++)
                    acc[mb][nb] = MFMA(af[mb], bf[nb], acc[mb][nb]);
        }
    }
    // ---- epilogue: stage fp32 in 64-row halves, store 512-B rows ----
    float bias4[4];
#pragma unroll
    for (int nb = 0; nb < 4; nb++) bias4[nb] = bias[n0 + wn + nb * 16 + (l & 15)];
    float (*Sf)[132] = (float(*)[132])&sm[0][0][0];   // 64x132 fp32 = 33792 B
#pragma unroll
    for (int half = 0; half < 2; half++) {
        __syncthreads();
        if ((w >> 1) == half) {
#pragma unroll
            for (int mb = 0; mb < 4; mb++)
#pragma unroll
                for (int r = 0; r < 4; r++)
#pragma unroll
                    for (int nb = 0; nb < 4; nb++)
                        Sf[mb * 16 + (l >> 4) * 4 + r][wn + nb * 16 + (l & 15)] =
                            acc[mb][nb][r] + bias4[nb];
        }
        __syncthreads();
#pragma unroll
        for (int it = 0; it < 8; it++) {
            int rr = it * 8 + w * 2 + (l >> 5);
            int m = m0 + half * 64 + rr;
            if (m < Mv)
                *(float4*)(out + (size_t)m * 1024 + n0 + (l & 31) * 4) =
                    *(const float4*)&Sf[rr][(l & 31) * 4];
        }
    }
}

extern "C" void kernel_launch(void* const* d_in, const int* in_sizes, int n_in,
                              void* d_out, int out_size, void* d_ws, size_t ws_size,
                              hipStream_t stream) {
    (void)in_sizes; (void)n_in; (void)out_size; (void)ws_size;
    const float* x      = (const float*)d_in[0];
    const float* sinp   = (const float*)d_in[1];
    const float* cosp   = (const float*)d_in[2];
    const float* qkv_w  = (const float*)d_in[3];
    const float* proj_w = (const float*)d_in[4];
    const float* proj_b = (const float*)d_in[5];
    float* out = (float*)d_out;

    const size_t SZH = (size_t)BHv * LpD * 64;     // per Q/K/V tensor (bf16 elems)
    ushort_t* xb  = (ushort_t*)d_ws;               // [Mp][1024]
    ushort_t* qwb = xb + (size_t)Mp * 1024;        // [3072][1024]
    ushort_t* pwb = qwb + (size_t)3072 * 1024;     // [1024][1024]
    ushort_t* Qb  = pwb + (size_t)1024 * 1024;     // [BH][Lp][64]
    ushort_t* Kb  = Qb + SZH;
    ushort_t* Vb  = Kb + SZH;
    ushort_t* Vt  = Vb + SZH;                      // [BH][64][Lp]
    ushort_t* AO  = Vt + SZH;                      // [Mp][1024]

    dim3 blk(256);
    conv_bf16<<<dim3(Mp * 1024 / 1024), blk, 0, stream>>>(x, xb, Mv * 1024, Mp * 1024);
    conv_bf16<<<dim3(3072 * 1024 / 1024), blk, 0, stream>>>(qkv_w, qwb, 3072 * 1024, 3072 * 1024);
    conv_bf16<<<dim3(1024 * 1024 / 1024), blk, 0, stream>>>(proj_w, pwb, 1024 * 1024, 1024 * 1024);
    gemm_qkv<<<dim3(24, 129), blk, 0, stream>>>(xb, qwb, Qb, Kb, Vb);
    rope_bf16<<<dim3(2 * BHv * 1024 / 4), blk, 0, stream>>>(Qb, Kb, sinp, cosp);
    transpose_v<<<dim3(17, BHv), blk, 0, stream>>>(Vb, Vt);
    attn_mfma<<<dim3(17, BHv), blk, 0, stream>>>(Qb, Kb, Vt, AO);
    gemm_proj<<<dim3(8, 129), blk, 0, stream>>>(AO, pwb, proj_b, out);
}

// Round 4
// 555.307 us; speedup vs baseline: 1.9520x; 1.9520x over previous
//
#include <hip/hip_runtime.h>

typedef unsigned short ushort_t;
typedef unsigned int uint_t;
typedef __attribute__((ext_vector_type(8))) short short8;
typedef __attribute__((ext_vector_type(4))) float f32x4;

#define Bv 16
#define Lv 1025
#define LpD 1088          // 17*64 padded sequence
#define Cv 1024
#define Hv 16
#define BHv 256
#define Mv 16400          // valid rows
#define Mp 16512          // 129*128 padded rows

#define MFMA(a, b, c) __builtin_amdgcn_mfma_f32_16x16x32_bf16(a, b, c, 0, 0, 0)

__device__ __forceinline__ ushort_t f2b(float x) {
    uint_t u = __float_as_uint(x);
    u = (u + 0x7FFFu + ((u >> 16) & 1u)) >> 16;   // RNE
    return (ushort_t)u;
}
__device__ __forceinline__ float b2f(ushort_t v) {
    return __uint_as_float(((uint_t)v) << 16);
}

// async global->LDS DMA, 16 B per lane; LDS dest = wave-uniform base + 16*lane
__device__ __forceinline__ void gl2lds16(const ushort_t* g, void* lds) {
    __builtin_amdgcn_global_load_lds(
        (const __attribute__((address_space(1))) void*)g,
        (__attribute__((address_space(3))) void*)lds, 16, 0, 0);
}

// XOR-swizzled frag read from an unpadded [rows][64] bf16 LDS tile:
// physical 16-B chunk p holds logical chunk p ^ (row & 7).
__device__ __forceinline__ short8 frag(const ushort_t* base, int row, int chunk) {
    return *(const short8*)(base + row * 64 + ((chunk ^ (row & 7)) << 3));
}

// ---------------- fp32 -> bf16 convert (pads tail with zeros) ---------------
__global__ __launch_bounds__(256) void conv_bf16(const float* __restrict__ s,
                                                 ushort_t* __restrict__ d,
                                                 int n_valid, int n_total) {
    int i = (blockIdx.x * 256 + threadIdx.x) * 4;
    if (i >= n_total) return;
    float4 v = make_float4(0.f, 0.f, 0.f, 0.f);
    if (i < n_valid) v = *(const float4*)(s + i);   // n_valid multiple of 4
    ushort4 o;
    o.x = f2b(v.x); o.y = f2b(v.y); o.z = f2b(v.z); o.w = f2b(v.w);
    *(ushort4*)(d + i) = o;
}

// ---------------- QKV GEMM: C[m][n] = sum_k A[m][k] W[n][k] -----------------
// m97-style K-loop: global_load_lds staging (XOR-swizzled chunks), 32 MFMA
// per iter per wave. Epilogue stages bf16 C-tile in LDS, 128-B line stores.
__global__ __launch_bounds__(256, 4) void gemm_qkv(const ushort_t* __restrict__ A,
                                                   const ushort_t* __restrict__ W,
                                                   ushort_t* __restrict__ Q,
                                                   ushort_t* __restrict__ K,
                                                   ushort_t* __restrict__ V) {
    __shared__ uint4 sm[2112];                     // 33792 B
    ushort_t* As = (ushort_t*)sm;                  // [128][64] swizzled
    ushort_t* Bs = As + 128 * 64;                  // [128][64] swizzled
    const int t = threadIdx.x;
    const int w = t >> 6, l = t & 63;
    const int m0 = blockIdx.y * 128, n0 = blockIdx.x * 128;
    const int wm = (w >> 1) * 64, wn = (w & 1) * 64;
    const int srow = (w * 32) + (l >> 3);          // staging row base for i=0
    const int scs = (l & 7) ^ (srow & 7);          // swizzled chunk (row&7 == (l>>3)&7)
    f32x4 acc[4][4] = {};
    for (int k0 = 0; k0 < 1024; k0 += 64) {
        __syncthreads();                           // prev frag reads done
#pragma unroll
        for (int i = 0; i < 4; i++) {
            int row = srow + i * 8;
            gl2lds16(A + (size_t)(m0 + row) * 1024 + k0 + scs * 8,
                     As + (w * 32 + i * 8) * 64);
            gl2lds16(W + (size_t)(n0 + row) * 1024 + k0 + scs * 8,
                     Bs + (w * 32 + i * 8) * 64);
        }
        __syncthreads();                           // drains vmcnt(0): LDS valid
#pragma unroll
        for (int kb = 0; kb < 2; kb++) {
            short8 af[4], bf[4];
#pragma unroll
            for (int mb = 0; mb < 4; mb++)
                af[mb] = frag(As, wm + mb * 16 + (l & 15), kb * 4 + (l >> 4));
#pragma unroll
            for (int nb = 0; nb < 4; nb++)
                bf[nb] = frag(Bs, wn + nb * 16 + (l & 15), kb * 4 + (l >> 4));
#pragma unroll
            for (int mb = 0; mb < 4; mb++)
#pragma unroll
                for (int nb = 0; nb < 4; nb++)
                    acc[mb][nb] = MFMA(af[mb], bf[nb], acc[mb][nb]);
        }
    }
    // ---- epilogue: LDS-staged, coalesced 128-B stores ----
    __syncthreads();
    ushort_t (*St)[132] = (ushort_t(*)[132])sm;    // 128x132 bf16 = 33792 B
#pragma unroll
    for (int mb = 0; mb < 4; mb++)
#pragma unroll
        for (int r = 0; r < 4; r++)
#pragma unroll
            for (int nb = 0; nb < 4; nb++)
                St[wm + mb * 16 + (l >> 4) * 4 + r][wn + nb * 16 + (l & 15)] =
                    f2b(acc[mb][nb][r]);
    __syncthreads();
#pragma unroll
    for (int it = 0; it < 8; it++) {
        int seg = it * 32 + w * 8 + (l >> 3);
        int mr = seg >> 1, p = seg & 1;
        int m = m0 + mr;
        if (m < Mv) {
            int b = m / 1025, lseq = m - b * 1025;
            int n = n0 + p * 64;
            int which = n >> 10, h = (n >> 6) & 15;
            ushort_t* dst = (which == 0) ? Q : ((which == 1) ? K : V);
            *(uint4*)(dst + ((size_t)(b * Hv + h) * LpD + lseq) * 64 + (l & 7) * 8) =
                *(const uint4*)&St[mr][p * 64 + (l & 7) * 8];
        }
    }
}

// ---------------- RoPE in-place on bf16 Q,K (rows l=1..1024) ----------------
__global__ __launch_bounds__(256) void rope_bf16(ushort_t* __restrict__ Qb,
                                                 ushort_t* __restrict__ Kb,
                                                 const float* __restrict__ sinp,
                                                 const float* __restrict__ cosp) {
    const int ROWS = BHv * 1024;
    int row = blockIdx.x * 4 + (threadIdx.x >> 6);
    int d = threadIdx.x & 63;
    ushort_t* arr = (row < ROWS) ? Qb : Kb;
    int r = (row < ROWS) ? row : row - ROWS;
    int bh = r >> 10, lm1 = r & 1023;
    size_t a = ((size_t)bh * LpD + lm1 + 1) * 64 + d;
    float f = b2f(arr[a]);
    float p = __shfl_xor(f, 32);
    p = (d < 32) ? -p : p;
    arr[a] = f2b(f * cosp[lm1 * 64 + d] + p * sinp[lm1 * 64 + d]);
}

// ---------------- V transpose: [BH][Lp][64] -> [BH][64][Lp] -----------------
__global__ __launch_bounds__(256) void transpose_v(const ushort_t* __restrict__ Vb,
                                                   ushort_t* __restrict__ Vt) {
    __shared__ ushort_t Ts[64][72];
    const int t = threadIdx.x;
    const int l0 = blockIdx.x * 64, bh = blockIdx.y;
#pragma unroll
    for (int i = 0; i < 2; i++) {
        int c = t + 256 * i; int row = c >> 3, cir = c & 7;
        *(uint4*)&Ts[row][cir * 8] =
            *(const uint4*)(Vb + ((size_t)bh * LpD + l0 + row) * 64 + cir * 8);
    }
    __syncthreads();
#pragma unroll
    for (int i = 0; i < 2; i++) {
        int c = t + 256 * i; int d = c >> 3, lg = c & 7;
        short8 v;
#pragma unroll
        for (int j = 0; j < 8; j++) v[j] = (short)Ts[lg * 8 + j][d];
        *(short8*)(Vt + ((size_t)bh * 64 + d) * LpD + l0 + lg * 8) = v;
    }
}

// ---------------- Attention: block = (q-tile 64, bh). Unnormalized exp. -----
__global__ __launch_bounds__(256, 4) void attn_mfma(const ushort_t* __restrict__ Qb,
                                                    const ushort_t* __restrict__ Kb,
                                                    const ushort_t* __restrict__ Vt,
                                                    ushort_t* __restrict__ AO) {
    __shared__ ushort_t Qs[64][72], Ks[64][72], Vs[64][72], Ps[64][72];
    const int t = threadIdx.x, w = t >> 6, l = t & 63;
    const int qt = blockIdx.x, bh = blockIdx.y;
    const int q0 = qt * 64;
    const size_t kbase = (size_t)bh * LpD * 64;
    const size_t vbase = (size_t)bh * 64 * LpD;
#pragma unroll
    for (int i = 0; i < 2; i++) {
        int c = t + 256 * i; int row = c >> 3, cir = c & 7;
        *(uint4*)&Qs[row][cir * 8] =
            *(const uint4*)(Qb + kbase + (size_t)(q0 + row) * 64 + cir * 8);
    }
    __syncthreads();
    // Q A-frags live in registers for the whole K loop
    short8 aq0 = *(const short8*)&Qs[w * 16 + (l & 15)][(l >> 4) * 8];
    short8 aq1 = *(const short8*)&Qs[w * 16 + (l & 15)][32 + (l >> 4) * 8];
    f32x4 o[4] = {};
    float sume[4] = {0.f, 0.f, 0.f, 0.f};
    const float CE = 0.18033688011112042f;  // log2(e)/8: exp(s/8) = exp2(s*CE)

    for (int kt = 0; kt < 17; kt++) {
        __syncthreads();
#pragma unroll
        for (int i = 0; i < 2; i++) {
            int c = t + 256 * i; int row = c >> 3, cir = c & 7;
            *(uint4*)&Ks[row][cir * 8] =
                *(const uint4*)(Kb + kbase + (size_t)(kt * 64 + row) * 64 + cir * 8);
            *(uint4*)&Vs[row][cir * 8] =
                *(const uint4*)(Vt + vbase + (size_t)row * LpD + kt * 64 + cir * 8);
        }
        __syncthreads();
#pragma unroll
        for (int cb = 0; cb < 4; cb++) {
            short8 bk0 = *(const short8*)&Ks[cb * 16 + (l & 15)][(l >> 4) * 8];
            short8 bk1 = *(const short8*)&Ks[cb * 16 + (l & 15)][32 + (l >> 4) * 8];
            f32x4 s = {};
            s = MFMA(aq0, bk0, s);
            s = MFMA(aq1, bk1, s);
            int key = kt * 64 + cb * 16 + (l & 15);
            bool valid = key < Lv;   // padded keys must contribute exactly 0
#pragma unroll
            for (int r = 0; r < 4; r++) {
                float p = valid ? exp2f(s[r] * CE) : 0.f;
                sume[r] += p;
                Ps[w * 16 + (l >> 4) * 4 + r][cb * 16 + (l & 15)] = f2b(p);
            }
        }
        // own-wave rows only -> no barrier; compiler inserts lgkmcnt waits
        short8 ap0 = *(const short8*)&Ps[w * 16 + (l & 15)][(l >> 4) * 8];
        short8 ap1 = *(const short8*)&Ps[w * 16 + (l & 15)][32 + (l >> 4) * 8];
#pragma unroll
        for (int cb = 0; cb < 4; cb++) {
            short8 bv0 = *(const short8*)&Vs[cb * 16 + (l & 15)][(l >> 4) * 8];
            short8 bv1 = *(const short8*)&Vs[cb * 16 + (l & 15)][32 + (l >> 4) * 8];
            o[cb] = MFMA(ap0, bv0, o[cb]);
            o[cb] = MFMA(ap1, bv1, o[cb]);
        }
    }
#pragma unroll
    for (int r = 0; r < 4; r++) {
        float s_ = sume[r];
        s_ += __shfl_xor(s_, 1); s_ += __shfl_xor(s_, 2);
        s_ += __shfl_xor(s_, 4); s_ += __shfl_xor(s_, 8);
        sume[r] = 1.f / s_;      // row sums; row map matches C-layout rows
    }
    const int b = bh >> 4, h = bh & 15;
#pragma unroll
    for (int r = 0; r < 4; r++) {
        int lq = q0 + w * 16 + (l >> 4) * 4 + r;
        if (lq >= Lv) continue;
        size_t ob = ((size_t)(b * 1025 + lq)) * 1024 + h * 64;
#pragma unroll
        for (int cb = 0; cb < 4; cb++)
            AO[ob + cb * 16 + (l & 15)] = f2b(o[cb][r] * sume[r]);
    }
}

// ---------------- Proj GEMM + bias, fp32 out --------------------------------
__global__ __launch_bounds__(256, 4) void gemm_proj(const ushort_t* __restrict__ A,
                                                    const ushort_t* __restrict__ W,
                                                    const float* __restrict__ bias,
                                                    float* __restrict__ out) {
    __shared__ uint4 sm[2112];                     // 33792 B
    ushort_t* As = (ushort_t*)sm;
    ushort_t* Bs = As + 128 * 64;
    const int t = threadIdx.x;
    const int w = t >> 6, l = t & 63;
    const int m0 = blockIdx.y * 128, n0 = blockIdx.x * 128;
    const int wm = (w >> 1) * 64, wn = (w & 1) * 64;
    const int srow = (w * 32) + (l >> 3);
    const int scs = (l & 7) ^ (srow & 7);
    f32x4 acc[4][4] = {};
    for (int k0 = 0; k0 < 1024; k0 += 64) {
        __syncthreads();
#pragma unroll
        for (int i = 0; i < 4; i++) {
            int row = srow + i * 8;
            gl2lds16(A + (size_t)(m0 + row) * 1024 + k0 + scs * 8,
                     As + (w * 32 + i * 8) * 64);
            gl2lds16(W + (size_t)(n0 + row) * 1024 + k0 + scs * 8,
                     Bs + (w * 32 + i * 8) * 64);
        }
        __syncthreads();
#pragma unroll
        for (int kb = 0; kb < 2; kb++) {
            short8 af[4], bf[4];
#pragma unroll
            for (int mb = 0; mb < 4; mb++)
                af[mb] = frag(As, wm + mb * 16 + (l & 15), kb * 4 + (l >> 4));
#pragma unroll
            for (int nb = 0; nb < 4; nb++)
                bf[nb] = frag(Bs, wn + nb * 16 + (l & 15), kb * 4 + (l >> 4));
#pragma unroll
            for (int mb = 0; mb < 4; mb++)
#pragma unroll
                for (int nb = 0; nb < 4; nb++)
                    acc[mb][nb] = MFMA(af[mb], bf[nb], acc[mb][nb]);
        }
    }
    // ---- epilogue: stage fp32 in 64-row halves, store 512-B rows ----
    float bias4[4];
#pragma unroll
    for (int nb = 0; nb < 4; nb++) bias4[nb] = bias[n0 + wn + nb * 16 + (l & 15)];
    float (*Sf)[132] = (float(*)[132])sm;          // 64x132 fp32 = 33792 B
#pragma unroll
    for (int half = 0; half < 2; half++) {
        __syncthreads();
        if ((w >> 1) == half) {
#pragma unroll
            for (int mb = 0; mb < 4; mb++)
#pragma unroll
                for (int r = 0; r < 4; r++)
#pragma unroll
                    for (int nb = 0; nb < 4; nb++)
                        Sf[mb * 16 + (l >> 4) * 4 + r][wn + nb * 16 + (l & 15)] =
                            acc[mb][nb][r] + bias4[nb];
        }
        __syncthreads();
#pragma unroll
        for (int it = 0; it < 8; it++) {
            int rr = it * 8 + w * 2 + (l >> 5);
            int m = m0 + half * 64 + rr;
            if (m < Mv)
                *(float4*)(out + (size_t)m * 1024 + n0 + (l & 31) * 4) =
                    *(const float4*)&Sf[rr][(l & 31) * 4];
        }
    }
}

extern "C" void kernel_launch(void* const* d_in, const int* in_sizes, int n_in,
                              void* d_out, int out_size, void* d_ws, size_t ws_size,
                              hipStream_t stream) {
    (void)in_sizes; (void)n_in; (void)out_size; (void)ws_size;
    const float* x      = (const float*)d_in[0];
    const float* sinp   = (const float*)d_in[1];
    const float* cosp   = (const float*)d_in[2];
    const float* qkv_w  = (const float*)d_in[3];
    const float* proj_w = (const float*)d_in[4];
    const float* proj_b = (const float*)d_in[5];
    float* out = (float*)d_out;

    const size_t SZH = (size_t)BHv * LpD * 64;     // per Q/K/V tensor (bf16 elems)
    ushort_t* xb  = (ushort_t*)d_ws;               // [Mp][1024]
    ushort_t* qwb = xb + (size_t)Mp * 1024;        // [3072][1024]
    ushort_t* pwb = qwb + (size_t)3072 * 1024;     // [1024][1024]
    ushort_t* Qb  = pwb + (size_t)1024 * 1024;     // [BH][Lp][64]
    ushort_t* Kb  = Qb + SZH;
    ushort_t* Vb  = Kb + SZH;
    ushort_t* Vt  = Vb + SZH;                      // [BH][64][Lp]
    ushort_t* AO  = Vt + SZH;                      // [Mp][1024]

    dim3 blk(256);
    conv_bf16<<<dim3(Mp * 1024 / 1024), blk, 0, stream>>>(x, xb, Mv * 1024, Mp * 1024);
    conv_bf16<<<dim3(3072 * 1024 / 1024), blk, 0, stream>>>(qkv_w, qwb, 3072 * 1024, 3072 * 1024);
    conv_bf16<<<dim3(1024 * 1024 / 1024), blk, 0, stream>>>(proj_w, pwb, 1024 * 1024, 1024 * 1024);
    gemm_qkv<<<dim3(24, 129), blk, 0, stream>>>(xb, qwb, Qb, Kb, Vb);
    rope_bf16<<<dim3(2 * BHv * 1024 / 4), blk, 0, stream>>>(Qb, Kb, sinp, cosp);
    transpose_v<<<dim3(17, BHv), blk, 0, stream>>>(Vb, Vt);
    attn_mfma<<<dim3(17, BHv), blk, 0, stream>>>(Qb, Kb, Vt, AO);
    gemm_proj<<<dim3(8, 129), blk, 0, stream>>>(AO, pwb, proj_b, out);
}

// Round 5
// 527.268 us; speedup vs baseline: 2.0558x; 1.0532x over previous
//
#include <hip/hip_runtime.h>

typedef unsigned short ushort_t;
typedef unsigned int uint_t;
typedef __attribute__((ext_vector_type(8))) short short8;
typedef __attribute__((ext_vector_type(4))) float f32x4;

#define Bv 16
#define Lv 1025
#define LpD 1088          // 17*64 padded sequence
#define Cv 1024
#define Hv 16
#define BHv 256
#define Mv 16400          // valid rows
#define Mp 16512          // 129*128 padded rows

#define MFMA(a, b, c) __builtin_amdgcn_mfma_f32_16x16x32_bf16(a, b, c, 0, 0, 0)

__device__ __forceinline__ ushort_t f2b(float x) {
    uint_t u = __float_as_uint(x);
    u = (u + 0x7FFFu + ((u >> 16) & 1u)) >> 16;   // RNE
    return (ushort_t)u;
}
__device__ __forceinline__ float b2f(ushort_t v) {
    return __uint_as_float(((uint_t)v) << 16);
}
// packed f32x2 -> bf16x2 (1 VALU op on gfx950; RNE)
__device__ __forceinline__ uint_t pk2(float a, float b) {
#if __has_builtin(__builtin_amdgcn_cvt_pk_bf16_f32)
    typedef __attribute__((ext_vector_type(2))) __bf16 bf16x2;
    bf16x2 r = __builtin_amdgcn_cvt_pk_bf16_f32(a, b);
    return *(uint_t*)&r;
#else
    return (uint_t)f2b(a) | ((uint_t)f2b(b) << 16);
#endif
}

// async global->LDS DMA, 16 B per lane; LDS dest = wave-uniform base + 16*lane
__device__ __forceinline__ void gl2lds16(const ushort_t* g, void* lds) {
    __builtin_amdgcn_global_load_lds(
        (const __attribute__((address_space(1))) void*)g,
        (__attribute__((address_space(3))) void*)lds, 16, 0, 0);
}

// XOR-swizzled frag read from an unpadded [rows][64] bf16 LDS tile:
// physical 16-B chunk p holds logical chunk p ^ (row & 7).
__device__ __forceinline__ short8 frag(const ushort_t* base, int row, int chunk) {
    return *(const short8*)(base + row * 64 + ((chunk ^ (row & 7)) << 3));
}

// ---------------- fp32 -> bf16 convert (pads tail with zeros) ---------------
__global__ __launch_bounds__(256) void conv_bf16(const float* __restrict__ s,
                                                 ushort_t* __restrict__ d,
                                                 int n_valid, int n_total) {
    int i = (blockIdx.x * 256 + threadIdx.x) * 4;
    if (i >= n_total) return;
    float4 v = make_float4(0.f, 0.f, 0.f, 0.f);
    if (i < n_valid) v = *(const float4*)(s + i);   // n_valid multiple of 4
    ushort4 o;
    o.x = f2b(v.x); o.y = f2b(v.y); o.z = f2b(v.z); o.w = f2b(v.w);
    *(ushort4*)(d + i) = o;
}

// ---------------- QKV GEMM: C[m][n] = sum_k A[m][k] W[n][k] -----------------
__global__ __launch_bounds__(256, 4) void gemm_qkv(const ushort_t* __restrict__ A,
                                                   const ushort_t* __restrict__ W,
                                                   ushort_t* __restrict__ Q,
                                                   ushort_t* __restrict__ K,
                                                   ushort_t* __restrict__ V) {
    __shared__ uint4 sm[2112];                     // 33792 B
    ushort_t* As = (ushort_t*)sm;                  // [128][64] swizzled
    ushort_t* Bs = As + 128 * 64;                  // [128][64] swizzled
    const int t = threadIdx.x;
    const int w = t >> 6, l = t & 63;
    const int m0 = blockIdx.y * 128, n0 = blockIdx.x * 128;
    const int wm = (w >> 1) * 64, wn = (w & 1) * 64;
    const int srow = (w * 32) + (l >> 3);          // staging row base for i=0
    const int scs = (l & 7) ^ (srow & 7);          // swizzled chunk
    f32x4 acc[4][4] = {};
    for (int k0 = 0; k0 < 1024; k0 += 64) {
        __syncthreads();                           // prev frag reads done
#pragma unroll
        for (int i = 0; i < 4; i++) {
            int row = srow + i * 8;
            gl2lds16(A + (size_t)(m0 + row) * 1024 + k0 + scs * 8,
                     As + (w * 32 + i * 8) * 64);
            gl2lds16(W + (size_t)(n0 + row) * 1024 + k0 + scs * 8,
                     Bs + (w * 32 + i * 8) * 64);
        }
        __syncthreads();                           // drains vmcnt(0): LDS valid
#pragma unroll
        for (int kb = 0; kb < 2; kb++) {
            short8 af[4], bf[4];
#pragma unroll
            for (int mb = 0; mb < 4; mb++)
                af[mb] = frag(As, wm + mb * 16 + (l & 15), kb * 4 + (l >> 4));
#pragma unroll
            for (int nb = 0; nb < 4; nb++)
                bf[nb] = frag(Bs, wn + nb * 16 + (l & 15), kb * 4 + (l >> 4));
#pragma unroll
            for (int mb = 0; mb < 4; mb++)
#pragma unroll
                for (int nb = 0; nb < 4; nb++)
                    acc[mb][nb] = MFMA(af[mb], bf[nb], acc[mb][nb]);
        }
    }
    // ---- epilogue: LDS-staged, coalesced 128-B stores ----
    __syncthreads();
    ushort_t (*St)[132] = (ushort_t(*)[132])sm;    // 128x132 bf16 = 33792 B
#pragma unroll
    for (int mb = 0; mb < 4; mb++)
#pragma unroll
        for (int r = 0; r < 4; r++)
#pragma unroll
            for (int nb = 0; nb < 4; nb++)
                St[wm + mb * 16 + (l >> 4) * 4 + r][wn + nb * 16 + (l & 15)] =
                    f2b(acc[mb][nb][r]);
    __syncthreads();
#pragma unroll
    for (int it = 0; it < 8; it++) {
        int seg = it * 32 + w * 8 + (l >> 3);
        int mr = seg >> 1, p = seg & 1;
        int m = m0 + mr;
        if (m < Mv) {
            int b = m / 1025, lseq = m - b * 1025;
            int n = n0 + p * 64;
            int which = n >> 10, h = (n >> 6) & 15;
            ushort_t* dst = (which == 0) ? Q : ((which == 1) ? K : V);
            *(uint4*)(dst + ((size_t)(b * Hv + h) * LpD + lseq) * 64 + (l & 7) * 8) =
                *(const uint4*)&St[mr][p * 64 + (l & 7) * 8];
        }
    }
}

// ---------------- RoPE in-place on bf16 Q,K (rows l=1..1024) ----------------
__global__ __launch_bounds__(256) void rope_bf16(ushort_t* __restrict__ Qb,
                                                 ushort_t* __restrict__ Kb,
                                                 const float* __restrict__ sinp,
                                                 const float* __restrict__ cosp) {
    const int ROWS = BHv * 1024;
    int row = blockIdx.x * 4 + (threadIdx.x >> 6);
    int d = threadIdx.x & 63;
    ushort_t* arr = (row < ROWS) ? Qb : Kb;
    int r = (row < ROWS) ? row : row - ROWS;
    int bh = r >> 10, lm1 = r & 1023;
    size_t a = ((size_t)bh * LpD + lm1 + 1) * 64 + d;
    float f = b2f(arr[a]);
    float p = __shfl_xor(f, 32);
    p = (d < 32) ? -p : p;
    arr[a] = f2b(f * cosp[lm1 * 64 + d] + p * sinp[lm1 * 64 + d]);
}

// ---------------- V transpose: [BH][Lp][64] -> [BH][64][Lp] -----------------
__global__ __launch_bounds__(256) void transpose_v(const ushort_t* __restrict__ Vb,
                                                   ushort_t* __restrict__ Vt) {
    __shared__ ushort_t Ts[64][72];
    const int t = threadIdx.x;
    const int l0 = blockIdx.x * 64, bh = blockIdx.y;
#pragma unroll
    for (int i = 0; i < 2; i++) {
        int c = t + 256 * i; int row = c >> 3, cir = c & 7;
        *(uint4*)&Ts[row][cir * 8] =
            *(const uint4*)(Vb + ((size_t)bh * LpD + l0 + row) * 64 + cir * 8);
    }
    __syncthreads();
#pragma unroll
    for (int i = 0; i < 2; i++) {
        int c = t + 256 * i; int d = c >> 3, lg = c & 7;
        short8 v;
#pragma unroll
        for (int j = 0; j < 8; j++) v[j] = (short)Ts[lg * 8 + j][d];
        *(short8*)(Vt + ((size_t)bh * 64 + d) * LpD + l0 + lg * 8) = v;
    }
}

// ---------------- Attention: block = (q-tile 64, bh). Unnormalized exp. -----
// DMA-staged K/V/Q tiles (XOR swizzle), pk-bf16 P conversion, row-sums via
// ones-vector MFMA on the idle matrix pipe.
__global__ __launch_bounds__(256, 4) void attn_mfma(const ushort_t* __restrict__ Qb,
                                                    const ushort_t* __restrict__ Kb,
                                                    const ushort_t* __restrict__ Vt,
                                                    ushort_t* __restrict__ AO) {
    __shared__ ushort_t Qs[64 * 64], Ks[64 * 64], Vs[64 * 64];  // swizzled
    __shared__ ushort_t Ps[64][72];
    const int t = threadIdx.x, w = t >> 6, l = t & 63;
    const int qt = blockIdx.x, bh = blockIdx.y;
    const int q0 = qt * 64;
    const size_t kbase = (size_t)bh * LpD * 64;
    const size_t vbase = (size_t)bh * 64 * LpD;
    const int scs = (l & 7) ^ ((l >> 3) & 7);      // swizzled chunk for staging

#pragma unroll
    for (int i = 0; i < 2; i++) {                  // Q tile: 16 rows per wave
        int row = w * 16 + i * 8 + (l >> 3);
        gl2lds16(Qb + kbase + (size_t)(q0 + row) * 64 + scs * 8,
                 Qs + (w * 16 + i * 8) * 64);
    }
    __syncthreads();
    short8 aq0 = frag(Qs, w * 16 + (l & 15), l >> 4);
    short8 aq1 = frag(Qs, w * 16 + (l & 15), 4 + (l >> 4));

    short8 ones;
#pragma unroll
    for (int j = 0; j < 8; j++) ones[j] = (short)0x3F80;   // 1.0 bf16
    f32x4 o[4] = {};
    f32x4 sacc = {};
    const float CE = 0.18033688011112042f;  // log2(e)/8: exp(s/8) = exp2(s*CE)

    for (int kt = 0; kt < 17; kt++) {
        __syncthreads();                           // prev tile reads done
#pragma unroll
        for (int i = 0; i < 2; i++) {
            int row = w * 16 + i * 8 + (l >> 3);
            gl2lds16(Kb + kbase + (size_t)(kt * 64 + row) * 64 + scs * 8,
                     Ks + (w * 16 + i * 8) * 64);
            gl2lds16(Vt + vbase + (size_t)row * LpD + kt * 64 + scs * 8,
                     Vs + (w * 16 + i * 8) * 64);
        }
        __syncthreads();                           // DMA drained: tiles valid
#pragma unroll
        for (int cb = 0; cb < 4; cb++) {
            short8 bk0 = frag(Ks, cb * 16 + (l & 15), l >> 4);
            short8 bk1 = frag(Ks, cb * 16 + (l & 15), 4 + (l >> 4));
            f32x4 s = {};
            s = MFMA(aq0, bk0, s);
            s = MFMA(aq1, bk1, s);
            float p4[4];
#pragma unroll
            for (int r = 0; r < 4; r++) p4[r] = exp2f(s[r] * CE);
            if (kt == 16) {                        // uniform branch: mask pad keys
                int key = 1024 + cb * 16 + (l & 15);
                if (key >= Lv) { p4[0] = p4[1] = p4[2] = p4[3] = 0.f; }
            }
            uint_t pk01 = pk2(p4[0], p4[1]);
            uint_t pk23 = pk2(p4[2], p4[3]);
            ushort_t* pr = &Ps[w * 16 + (l >> 4) * 4][cb * 16 + (l & 15)];
            pr[0 * 72] = (ushort_t)pk01;
            pr[1 * 72] = (ushort_t)(pk01 >> 16);
            pr[2 * 72] = (ushort_t)pk23;
            pr[3 * 72] = (ushort_t)(pk23 >> 16);
        }
        // own-wave rows only -> no barrier; compiler inserts lgkmcnt waits
        short8 ap0 = *(const short8*)&Ps[w * 16 + (l & 15)][(l >> 4) * 8];
        short8 ap1 = *(const short8*)&Ps[w * 16 + (l & 15)][32 + (l >> 4) * 8];
        sacc = MFMA(ap0, ones, sacc);              // exact row-sums of rounded P
        sacc = MFMA(ap1, ones, sacc);
#pragma unroll
        for (int cb = 0; cb < 4; cb++) {
            short8 bv0 = frag(Vs, cb * 16 + (l & 15), l >> 4);
            short8 bv1 = frag(Vs, cb * 16 + (l & 15), 4 + (l >> 4));
            o[cb] = MFMA(ap0, bv0, o[cb]);
            o[cb] = MFMA(ap1, bv1, o[cb]);
        }
    }
    const int b = bh >> 4, h = bh & 15;
#pragma unroll
    for (int r = 0; r < 4; r++) {
        int lq = q0 + w * 16 + (l >> 4) * 4 + r;
        if (lq >= Lv) continue;
        float inv = 1.f / sacc[r];
        size_t ob = ((size_t)(b * 1025 + lq)) * 1024 + h * 64;
#pragma unroll
        for (int cb = 0; cb < 4; cb++)
            AO[ob + cb * 16 + (l & 15)] = f2b(o[cb][r] * inv);
    }
}

// ---------------- Proj GEMM + bias, fp32 out --------------------------------
__global__ __launch_bounds__(256, 4) void gemm_proj(const ushort_t* __restrict__ A,
                                                    const ushort_t* __restrict__ W,
                                                    const float* __restrict__ bias,
                                                    float* __restrict__ out) {
    __shared__ uint4 sm[2112];                     // 33792 B
    ushort_t* As = (ushort_t*)sm;
    ushort_t* Bs = As + 128 * 64;
    const int t = threadIdx.x;
    const int w = t >> 6, l = t & 63;
    const int m0 = blockIdx.y * 128, n0 = blockIdx.x * 128;
    const int wm = (w >> 1) * 64, wn = (w & 1) * 64;
    const int srow = (w * 32) + (l >> 3);
    const int scs = (l & 7) ^ (srow & 7);
    f32x4 acc[4][4] = {};
    for (int k0 = 0; k0 < 1024; k0 += 64) {
        __syncthreads();
#pragma unroll
        for (int i = 0; i < 4; i++) {
            int row = srow + i * 8;
            gl2lds16(A + (size_t)(m0 + row) * 1024 + k0 + scs * 8,
                     As + (w * 32 + i * 8) * 64);
            gl2lds16(W + (size_t)(n0 + row) * 1024 + k0 + scs * 8,
                     Bs + (w * 32 + i * 8) * 64);
        }
        __syncthreads();
#pragma unroll
        for (int kb = 0; kb < 2; kb++) {
            short8 af[4], bf[4];
#pragma unroll
            for (int mb = 0; mb < 4; mb++)
                af[mb] = frag(As, wm + mb * 16 + (l & 15), kb * 4 + (l >> 4));
#pragma unroll
            for (int nb = 0; nb < 4; nb++)
                bf[nb] = frag(Bs, wn + nb * 16 + (l & 15), kb * 4 + (l >> 4));
#pragma unroll
            for (int mb = 0; mb < 4; mb++)
#pragma unroll
                for (int nb = 0; nb < 4; nb++)
                    acc[mb][nb] = MFMA(af[mb], bf[nb], acc[mb][nb]);
        }
    }
    // ---- epilogue: stage fp32 in 64-row halves, store 512-B rows ----
    float bias4[4];
#pragma unroll
    for (int nb = 0; nb < 4; nb++) bias4[nb] = bias[n0 + wn + nb * 16 + (l & 15)];
    float (*Sf)[132] = (float(*)[132])sm;          // 64x132 fp32 = 33792 B
#pragma unroll
    for (int half = 0; half < 2; half++) {
        __syncthreads();
        if ((w >> 1) == half) {
#pragma unroll
            for (int mb = 0; mb < 4; mb++)
#pragma unroll
                for (int r = 0; r < 4; r++)
#pragma unroll
                    for (int nb = 0; nb < 4; nb++)
                        Sf[mb * 16 + (l >> 4) * 4 + r][wn + nb * 16 + (l & 15)] =
                            acc[mb][nb][r] + bias4[nb];
        }
        __syncthreads();
#pragma unroll
        for (int it = 0; it < 8; it++) {
            int rr = it * 8 + w * 2 + (l >> 5);
            int m = m0 + half * 64 + rr;
            if (m < Mv)
                *(float4*)(out + (size_t)m * 1024 + n0 + (l & 31) * 4) =
                    *(const float4*)&Sf[rr][(l & 31) * 4];
        }
    }
}

extern "C" void kernel_launch(void* const* d_in, const int* in_sizes, int n_in,
                              void* d_out, int out_size, void* d_ws, size_t ws_size,
                              hipStream_t stream) {
    (void)in_sizes; (void)n_in; (void)out_size; (void)ws_size;
    const float* x      = (const float*)d_in[0];
    const float* sinp   = (const float*)d_in[1];
    const float* cosp   = (const float*)d_in[2];
    const float* qkv_w  = (const float*)d_in[3];
    const float* proj_w = (const float*)d_in[4];
    const float* proj_b = (const float*)d_in[5];
    float* out = (float*)d_out;

    const size_t SZH = (size_t)BHv * LpD * 64;     // per Q/K/V tensor (bf16 elems)
    ushort_t* xb  = (ushort_t*)d_ws;               // [Mp][1024]
    ushort_t* qwb = xb + (size_t)Mp * 1024;        // [3072][1024]
    ushort_t* pwb = qwb + (size_t)3072 * 1024;     // [1024][1024]
    ushort_t* Qb  = pwb + (size_t)1024 * 1024;     // [BH][Lp][64]
    ushort_t* Kb  = Qb + SZH;
    ushort_t* Vb  = Kb + SZH;
    ushort_t* Vt  = Vb + SZH;                      // [BH][64][Lp]
    ushort_t* AO  = Vt + SZH;                      // [Mp][1024]

    dim3 blk(256);
    conv_bf16<<<dim3(Mp * 1024 / 1024), blk, 0, stream>>>(x, xb, Mv * 1024, Mp * 1024);
    conv_bf16<<<dim3(3072 * 1024 / 1024), blk, 0, stream>>>(qkv_w, qwb, 3072 * 1024, 3072 * 1024);
    conv_bf16<<<dim3(1024 * 1024 / 1024), blk, 0, stream>>>(proj_w, pwb, 1024 * 1024, 1024 * 1024);
    gemm_qkv<<<dim3(24, 129), blk, 0, stream>>>(xb, qwb, Qb, Kb, Vb);
    rope_bf16<<<dim3(2 * BHv * 1024 / 4), blk, 0, stream>>>(Qb, Kb, sinp, cosp);
    transpose_v<<<dim3(17, BHv), blk, 0, stream>>>(Vb, Vt);
    attn_mfma<<<dim3(17, BHv), blk, 0, stream>>>(Qb, Kb, Vt, AO);
    gemm_proj<<<dim3(8, 129), blk, 0, stream>>>(AO, pwb, proj_b, out);
}